// Round 7
// baseline (266.436 us; speedup 1.0000x reference)
//
#include <hip/hip_runtime.h>

using bf16x8 = __attribute__((ext_vector_type(8))) short;
using f32x4  = __attribute__((ext_vector_type(4))) float;
using u32x4  = __attribute__((ext_vector_type(4))) unsigned int;

__device__ __forceinline__ unsigned short f2bf(float f) {
  unsigned int u = __builtin_bit_cast(unsigned int, f);
  u += 0x7FFF + ((u >> 16) & 1);               // RNE
  return (unsigned short)(u >> 16);
}
__device__ __forceinline__ bf16x8 lds_frag(const unsigned short* p) {
  return __builtin_bit_cast(bf16x8, *(const u32x4*)p);
}
// async global->LDS, 16B per lane; LDS dest = wave-uniform base + lane*16
__device__ __forceinline__ void async_copy16(const unsigned short* g, unsigned short* l) {
  __builtin_amdgcn_global_load_lds(
      (const __attribute__((address_space(1))) unsigned int*)g,
      (__attribute__((address_space(3))) unsigned int*)l, 16, 0, 0);
}

// Fused prep: cast x -> bf16 (8192 blocks) + transpose w_qkv (1536) +
// transpose w_out (512). Branch on blockIdx range (block-uniform).
__global__ void prep_k(const float* __restrict__ x, unsigned short* __restrict__ xb,
                       const float* __restrict__ w_qkv, unsigned short* __restrict__ wqkvT,
                       const float* __restrict__ w_out, unsigned short* __restrict__ woutT) {
  __shared__ float tile[32][33];
  const int b = blockIdx.x;
  if (b < 8192) {
    int i = (b * 256 + threadIdx.x) * 8;
    if (i < 16384 * 1024) {
      unsigned short r[8];
      #pragma unroll
      for (int j = 0; j < 8; ++j) r[j] = f2bf(x[i + j]);
      *(u32x4*)&xb[i] = *(u32x4*)r;
    }
    return;
  }
  const float* in;
  unsigned short* out;
  int R, C, bx, by;
  if (b < 8192 + 1536) {                   // w_qkv: 1024x1536, grid 48x32
    int lb = b - 8192;
    bx = lb % 48; by = lb / 48;
    in = w_qkv; out = wqkvT; R = 1024; C = 1536;
  } else {                                 // w_out: 512x1024, grid 32x16
    int lb = b - 9728;
    bx = lb % 32; by = lb / 32;
    in = w_out; out = woutT; R = 512; C = 1024;
  }
  const int tx = threadIdx.x & 31, ty = threadIdx.x >> 5;   // 32 x 8
  const int c0 = bx * 32, r0 = by * 32;
  #pragma unroll
  for (int i = 0; i < 4; ++i)
    tile[ty + i * 8][tx] = in[(size_t)(r0 + ty + i * 8) * C + c0 + tx];
  __syncthreads();
  #pragma unroll
  for (int i = 0; i < 4; ++i)
    out[(size_t)(c0 + ty + i * 8) * R + r0 + tx] = f2bf(tile[tx][ty + i * 8]);
}

// C[M,N] = A[M,K] @ Bt[N,K]^T (+bias for fp32 out), bf16 in, fp32 accum.
// 256x256 tile, BK=64, 512 threads (8 waves, 2M x 4N), double-buffered LDS
// (128 KB), faithful 8-phase-per-2-K-tiles schedule (T3+T4+T5):
//  - LDS layout [256 rows][64 k], XOR-8 slot swizzle (slot = group ^ (row&7)).
//    VERIFIED conflict-free with this exact read addressing (rounds 0/1/5/6:
//    SQ_LDS_BANK_CONFLICT == 0).
//  - Staging granularity: 64-row full-K chunks (the only LDS-linear unit in
//    this layout). 8 chunks per K-tile, issued 2 PER PHASE (fine interleave,
//    the m196-isolated lever) in consume-matched order:
//       ph0: B0,B1   ph1: B2,B3   ph2: A0,A2   ph3: A1,A3   (for tile T+1)
//  - 2 publishes per tile, both counted vmcnt(2) (never 0 in steady state):
//       entry: {B0..B3, A0, A2} landed  (outstanding: A1,A3)
//       mid:   {A1, A3} landed          (outstanding: T+1's B0,B1)
//    Phases 2-3 need NO barrier (their k-half lives in published chunks).
//  - Race-freedom: T+1 staging targets buf^1 (not read during T); T's own
//    A1,A3 land into the active buffer at rows 64-127/192-255 which ph0 does
//    not read, and are published by the mid barrier before ph1 reads them.
template <typename OutT>
__global__ __launch_bounds__(512, 2)
void gemm_bt256(const unsigned short* __restrict__ A,
                const unsigned short* __restrict__ Bt,
                OutT* __restrict__ C,
                const float* __restrict__ bias,
                int M, int N, int K, int n_tiles, int mt_per_xcd) {
  __shared__ unsigned short Ash[2][256 * 64];   // 64 KB
  __shared__ unsigned short Bsh[2][256 * 64];   // 64 KB
  const int tid  = threadIdx.x;                 // 0..511
  const int wv   = tid >> 6, lane = tid & 63;
  const int quad = lane >> 4, l15 = lane & 15;
  const int wr   = wv >> 2, wc = wv & 3;        // 2M x 4N wave grid

  const int b = blockIdx.x;
  const int xcd = b & 7, local = b >> 3;        // grid % 8 == 0 -> bijective
  const int mt = xcd * mt_per_xcd + local / n_tiles;
  const int nt = local % n_tiles;
  const int m0 = mt * 256, n0 = nt * 256;

  // chunk c covers rows [c*64, c*64+64) full-K. lane: row = c*64 + (tid>>3),
  // slot = tid&7; global group g = slot ^ (row&7) = (tid&7) ^ ((tid>>3)&7)
  // (c-independent since 64 ≡ 0 mod 8). LDS lin offset within chunk = tid.
  const int g8 = ((tid & 7) ^ ((tid >> 3) & 7)) * 8;
  const unsigned short* pA[4];
  const unsigned short* pB[4];
  #pragma unroll
  for (int c = 0; c < 4; ++c) {
    int row = c * 64 + (tid >> 3);
    pA[c] = &A[(size_t)(m0 + row) * K + g8];
    pB[c] = &Bt[(size_t)(n0 + row) * K + g8];
  }

  f32x4 acc[8][4];
  #pragma unroll
  for (int i = 0; i < 8; ++i)
    #pragma unroll
    for (int j = 0; j < 4; ++j)
      acc[i][j] = (f32x4){0.f, 0.f, 0.f, 0.f};

  bf16x8 bfr[4];

  auto stageA = [&](int dst, int ko, int c) {
    async_copy16(pA[c] + ko, &Ash[dst][c * 4096 + tid * 8]);
  };
  auto stageB = [&](int dst, int ko, int c) {
    async_copy16(pB[c] + ko, &Bsh[dst][c * 4096 + tid * 8]);
  };

  // one quadrant phase: (mh, ks) -> 4 (or 8) ds_read_b128 + 16 MFMA
  auto phase = [&](int buf, int mh, int ks, bool loadB) {
    const unsigned short* As = Ash[buf];
    const unsigned short* Bs = Bsh[buf];
    const int swz = (((ks * 4 + quad) ^ (l15 & 7)) * 8);
    if (loadB) {
      #pragma unroll
      for (int n = 0; n < 4; ++n)
        bfr[n] = lds_frag(&Bs[(wc * 64 + n * 16 + l15) * 64 + swz]);
    }
    bf16x8 af[4];
    #pragma unroll
    for (int m = 0; m < 4; ++m)
      af[m] = lds_frag(&As[(wr * 128 + mh * 64 + m * 16 + l15) * 64 + swz]);
    __builtin_amdgcn_s_setprio(1);
    #pragma unroll
    for (int m = 0; m < 4; ++m)
      #pragma unroll
      for (int n = 0; n < 4; ++n)
        acc[mh * 4 + m][n] = __builtin_amdgcn_mfma_f32_16x16x32_bf16(
            af[m], bfr[n], acc[mh * 4 + m][n], 0, 0, 0);
    __builtin_amdgcn_s_setprio(0);
  };

  const int NT = K >> 6;
  // prologue: tile 0 chunks, consume-matched issue order
  stageB(0, 0, 0); stageB(0, 0, 1); stageB(0, 0, 2); stageB(0, 0, 3);
  stageA(0, 0, 0); stageA(0, 0, 2); stageA(0, 0, 1); stageA(0, 0, 3);

  for (int T = 0; T < NT; ++T) {
    const int buf = T & 1, nb = buf ^ 1;
    const int kn = (T + 1) * 64;
    const bool more = (T + 1) < NT;
    // entry publish: B0..3, A0, A2 of T landed (A1,A3 may be in flight)
    asm volatile("s_waitcnt lgkmcnt(0)" ::: "memory");
    asm volatile("s_waitcnt vmcnt(2)" ::: "memory");
    __builtin_amdgcn_s_barrier();
    asm volatile("" ::: "memory");
    // ph0: (mh0, ks0)
    if (more) { stageB(nb, kn, 0); stageB(nb, kn, 1); }
    phase(buf, 0, 0, true);
    // mid publish: A1, A3 of T landed (outstanding: T+1's B0,B1)
    asm volatile("s_waitcnt lgkmcnt(0)" ::: "memory");
    if (more) asm volatile("s_waitcnt vmcnt(2)" ::: "memory");
    else      asm volatile("s_waitcnt vmcnt(0)" ::: "memory");
    __builtin_amdgcn_s_barrier();
    asm volatile("" ::: "memory");
    // ph1: (mh1, ks0)
    if (more) { stageB(nb, kn, 2); stageB(nb, kn, 3); }
    phase(buf, 1, 0, false);
    // ph2: (mh0, ks1) — no barrier needed (same chunks, other k-half)
    if (more) { stageA(nb, kn, 0); stageA(nb, kn, 2); }
    phase(buf, 0, 1, true);
    // ph3: (mh1, ks1)
    if (more) { stageA(nb, kn, 1); stageA(nb, kn, 3); }
    phase(buf, 1, 1, false);
  }

  #pragma unroll
  for (int mf = 0; mf < 8; ++mf) {
    #pragma unroll
    for (int n = 0; n < 4; ++n) {
      int col = n0 + wc * 64 + n * 16 + l15;
      float badd = (bias != nullptr) ? bias[col] : 0.f;
      #pragma unroll
      for (int r = 0; r < 4; ++r) {
        int row = m0 + wr * 128 + mf * 16 + quad * 4 + r;
        if constexpr (sizeof(OutT) == 2)
          C[(size_t)row * N + col] = f2bf(acc[mf][n][r] + badd);
        else
          C[(size_t)row * N + col] = acc[mf][n][r] + badd;
      }
    }
  }
}

// Local attention (unchanged from round 6): one block per (head, window).
// 512 threads / 8 waves: wave wv owns m-tile wv. Two block-wide barriers.
// PV split into two k-halves so the P overlay fits Ksh (4KB/wave/half).
__global__ __launch_bounds__(512, 4)
void attn_local(const unsigned short* __restrict__ qkv,
                unsigned short* __restrict__ out) {
  __shared__ unsigned short Ksh[2 * 256 * 32];   // 32 KB
  __shared__ unsigned short VshT[64 * 256];      // 32 KB
  unsigned short* Psh = Ksh;

  const int tid  = threadIdx.x;
  const int wv   = tid >> 6, lane = tid & 63;
  const int quad = lane >> 4, l15 = lane & 15;
  const int h = blockIdx.x & 7, w = blockIdx.x >> 3;

  // stage K (k-tiled); rows j<128 of window 0 are zeros
  #pragma unroll
  for (int p = 0; p < 4; ++p) {
    int c = p * 512 + tid;                 // 2048 = 256 rows x 8 vec8-groups
    int j = c >> 3, sub = c & 7;
    u32x4 kvv = (u32x4){0, 0, 0, 0};
    if (!(w == 0 && j < 128)) {
      size_t base = (size_t)((w - 1) * 128 + j) * 1536 + h * 64 + sub * 8;
      kvv = *(const u32x4*)&qkv[base + 512];
    }
    *(u32x4*)&Ksh[(sub >> 2) * 8192 + j * 32 + (sub & 3) * 8] = kvv;
  }
  // stage V^T
  {
    const int n = tid & 63, kb8 = tid >> 6;
    #pragma unroll
    for (int kk = 0; kk < 4; ++kk) {
      int kb = kk * 8 + kb8;               // group 0..31, k0 = kb*8
      unsigned short tmp[8];
      if (w == 0 && kb < 16) {
        #pragma unroll
        for (int j = 0; j < 8; ++j) tmp[j] = 0;
      } else {
        #pragma unroll
        for (int j = 0; j < 8; ++j)
          tmp[j] = qkv[(size_t)((w - 1) * 128 + kb * 8 + j) * 1536 + 1024 + h * 64 + n];
      }
      *(u32x4*)&VshT[n * 256 + ((kb ^ (n & 7)) * 8)] = *(u32x4*)tmp;
    }
  }

  // Q fragments straight from global
  bf16x8 qf[2];
  {
    int tok = w * 128 + wv * 16 + l15;
    #pragma unroll
    for (int ks = 0; ks < 2; ++ks)
      qf[ks] = __builtin_bit_cast(
          bf16x8, *(const u32x4*)&qkv[(size_t)tok * 1536 + h * 64 + ks * 32 + quad * 8]);
  }

  __syncthreads();   // staging visible block-wide

  // scores
  float s[16][4];
  #pragma unroll
  for (int nt = 0; nt < 16; ++nt) {
    bf16x8 kf0 = lds_frag(&Ksh[0    + (nt * 16 + l15) * 32 + quad * 8]);
    bf16x8 kf1 = lds_frag(&Ksh[8192 + (nt * 16 + l15) * 32 + quad * 8]);
    f32x4 a = (f32x4){0.f, 0.f, 0.f, 0.f};
    a = __builtin_amdgcn_mfma_f32_16x16x32_bf16(qf[0], kf0, a, 0, 0, 0);
    a = __builtin_amdgcn_mfma_f32_16x16x32_bf16(qf[1], kf1, a, 0, 0, 0);
    #pragma unroll
    for (int r = 0; r < 4; ++r) s[nt][r] = a[r];
  }

  __syncthreads();   // all waves' Ksh reads complete -> safe to overlay P

  // masked softmax in registers
  #pragma unroll
  for (int r = 0; r < 4; ++r) {
    int lim = wv * 16 + quad * 4 + r + 128;
    float mx = -3.0e38f;
    #pragma unroll
    for (int nt = 0; nt < 16; ++nt) {
      float v = ((nt * 16 + l15) <= lim) ? s[nt][r] * 0.125f : -3.0e38f;
      s[nt][r] = v;
      mx = fmaxf(mx, v);
    }
    mx = fmaxf(mx, __shfl_xor(mx, 1));
    mx = fmaxf(mx, __shfl_xor(mx, 2));
    mx = fmaxf(mx, __shfl_xor(mx, 4));
    mx = fmaxf(mx, __shfl_xor(mx, 8));
    float sum = 0.f;
    #pragma unroll
    for (int nt = 0; nt < 16; ++nt) {
      float p = __expf(s[nt][r] - mx);
      s[nt][r] = p;
      sum += p;
    }
    sum += __shfl_xor(sum, 1);
    sum += __shfl_xor(sum, 2);
    sum += __shfl_xor(sum, 4);
    sum += __shfl_xor(sum, 8);
    float inv = 1.f / sum;
    #pragma unroll
    for (int nt = 0; nt < 16; ++nt) s[nt][r] *= inv;
  }

  // split PV through wave-private 4KB region
  f32x4 o[4];
  #pragma unroll
  for (int n2 = 0; n2 < 4; ++n2) o[n2] = (f32x4){0.f, 0.f, 0.f, 0.f};
  #pragma unroll
  for (int half = 0; half < 2; ++half) {
    if (half) {
      asm volatile("s_waitcnt lgkmcnt(0)" ::: "memory");
      __builtin_amdgcn_sched_barrier(0);
    }
    #pragma unroll
    for (int nt2 = 0; nt2 < 8; ++nt2) {
      int nt = half * 8 + nt2;
      #pragma unroll
      for (int r = 0; r < 4; ++r)
        Psh[wv * 2048 + (nt2 >> 1) * 512 + (quad * 4 + r) * 32 + (nt2 & 1) * 16 + l15] =
            f2bf(s[nt][r]);
    }
    asm volatile("s_waitcnt lgkmcnt(0)" ::: "memory");
    __builtin_amdgcn_sched_barrier(0);
    #pragma unroll
    for (int ks2 = 0; ks2 < 4; ++ks2) {
      int ks = half * 4 + ks2;
      bf16x8 pa = lds_frag(&Psh[wv * 2048 + ks2 * 512 + l15 * 32 + quad * 8]);
      #pragma unroll
      for (int n2 = 0; n2 < 4; ++n2) {
        bf16x8 vb = lds_frag(&VshT[(n2 * 16 + l15) * 256 + (((ks * 4 + quad) ^ (l15 & 7)) * 8)]);
        o[n2] = __builtin_amdgcn_mfma_f32_16x16x32_bf16(pa, vb, o[n2], 0, 0, 0);
      }
    }
  }
  int tokb = w * 128 + wv * 16 + quad * 4;
  #pragma unroll
  for (int n2 = 0; n2 < 4; ++n2)
    #pragma unroll
    for (int r = 0; r < 4; ++r)
      out[(size_t)(tokb + r) * 512 + h * 64 + n2 * 16 + l15] = f2bf(o[n2][r]);
}

extern "C" void kernel_launch(void* const* d_in, const int* in_sizes, int n_in,
                              void* d_out, int out_size, void* d_ws, size_t ws_size,
                              hipStream_t stream) {
  const float* x     = (const float*)d_in[0];  // 16384 x 1024 fp32
  const float* w_qkv = (const float*)d_in[1];  // 1024 x 1536 fp32
  const float* w_out = (const float*)d_in[2];  // 512 x 1024 fp32
  const float* b_out = (const float*)d_in[3];  // 1024 fp32
  float* out = (float*)d_out;                  // 16384 x 1024 fp32

  char* ws = (char*)d_ws;
  unsigned short* xb    = (unsigned short*)ws;                     // 16384x1024 bf16 (32 MB)
  unsigned short* wqkvT = (unsigned short*)(ws + 33554432);        // 1536x1024 (3 MB)
  unsigned short* woutT = (unsigned short*)(ws + 36700160);        // 1024x512  (1 MB)
  unsigned short* qkv   = (unsigned short*)(ws + 37748736);        // 16384x1536 (48 MB)
  unsigned short* attno = (unsigned short*)(ws + 88080384);        // 16384x512 (16 MB)

  // fused prep: cast (8192 blocks) + transpose w_qkv (1536) + transpose w_out (512)
  prep_k<<<10240, 256, 0, stream>>>(x, xb, w_qkv, wqkvT, w_out, woutT);
  // QKV: 64 m-tiles x 6 n-tiles (256^2); 8 m-tiles per xcd
  gemm_bt256<unsigned short><<<384, 512, 0, stream>>>(
      xb, wqkvT, qkv, nullptr, 16384, 1536, 1024, 6, 8);
  attn_local<<<1024, 512, 0, stream>>>(qkv, attno);
  // out-proj: 64 m-tiles x 4 n-tiles (256^2); 8 m-tiles per xcd
  gemm_bt256<float><<<256, 512, 0, stream>>>(
      attno, woutT, out, b_out, 16384, 1024, 512, 4, 8);
}

// Round 8
// 226.815 us; speedup vs baseline: 1.1747x; 1.1747x over previous
//
#include <hip/hip_runtime.h>

using bf16x8 = __attribute__((ext_vector_type(8))) short;
using f32x4  = __attribute__((ext_vector_type(4))) float;
using u32x4  = __attribute__((ext_vector_type(4))) unsigned int;

__device__ __forceinline__ unsigned short f2bf(float f) {
  unsigned int u = __builtin_bit_cast(unsigned int, f);
  u += 0x7FFF + ((u >> 16) & 1);               // RNE
  return (unsigned short)(u >> 16);
}
__device__ __forceinline__ bf16x8 lds_frag(const unsigned short* p) {
  return __builtin_bit_cast(bf16x8, *(const u32x4*)p);
}
// async global->LDS, 16B per lane; LDS dest = wave-uniform base + lane*16
__device__ __forceinline__ void async_copy16(const unsigned short* g, unsigned short* l) {
  __builtin_amdgcn_global_load_lds(
      (const __attribute__((address_space(1))) unsigned int*)g,
      (__attribute__((address_space(3))) unsigned int*)l, 16, 0, 0);
}

// Fused prep: cast x -> bf16 (8192 blocks) + transpose w_qkv (1536) +
// transpose w_out (512). Branch on blockIdx range (block-uniform).
__global__ void prep_k(const float* __restrict__ x, unsigned short* __restrict__ xb,
                       const float* __restrict__ w_qkv, unsigned short* __restrict__ wqkvT,
                       const float* __restrict__ w_out, unsigned short* __restrict__ woutT) {
  __shared__ float tile[32][33];
  const int b = blockIdx.x;
  if (b < 8192) {
    int i = (b * 256 + threadIdx.x) * 8;
    if (i < 16384 * 1024) {
      unsigned short r[8];
      #pragma unroll
      for (int j = 0; j < 8; ++j) r[j] = f2bf(x[i + j]);
      *(u32x4*)&xb[i] = *(u32x4*)r;
    }
    return;
  }
  const float* in;
  unsigned short* out;
  int R, C, bx, by;
  if (b < 8192 + 1536) {                   // w_qkv: 1024x1536, grid 48x32
    int lb = b - 8192;
    bx = lb % 48; by = lb / 48;
    in = w_qkv; out = wqkvT; R = 1024; C = 1536;
  } else {                                 // w_out: 512x1024, grid 32x16
    int lb = b - 9728;
    bx = lb % 32; by = lb / 32;
    in = w_out; out = woutT; R = 512; C = 1024;
  }
  const int tx = threadIdx.x & 31, ty = threadIdx.x >> 5;   // 32 x 8
  const int c0 = bx * 32, r0 = by * 32;
  #pragma unroll
  for (int i = 0; i < 4; ++i)
    tile[ty + i * 8][tx] = in[(size_t)(r0 + ty + i * 8) * C + c0 + tx];
  __syncthreads();
  #pragma unroll
  for (int i = 0; i < 4; ++i)
    out[(size_t)(c0 + ty + i * 8) * R + r0 + tx] = f2bf(tile[tx][ty + i * 8]);
}

// C[M,N] = A[M,K] @ Bt[N,K]^T (+bias for fp32 out), A/Bt bf16, fp32 accum.
// 128x128 tile, BK=64, global_load_lds staging with XOR bank swizzle
// (conflict-free, verified: SQ_LDS_BANK_CONFLICT == 0). Known-good m97
// structure. This round: occupancy 3 -> 4 blocks/CU (m114 mechanism: more
// co-resident blocks hide each other's barrier vmcnt drains; VGPR 60 <= 128
// cap, LDS 4x32KB = 128 <= 160). Out-proj's 1024-block grid becomes exactly
// one occupancy round. 256^2 deep-pipeline retired for good: 3 attempts all
// ~22% MfmaUtil — compiler inserts its own vmcnt(0) before ds_reads that
// depend on global_load_lds, and at 1 block/CU no TLP covers the drain.
template <typename OutT>
__global__ __launch_bounds__(256, 4)
void gemm_bt(const unsigned short* __restrict__ A,
             const unsigned short* __restrict__ Bt,
             OutT* __restrict__ C,
             const float* __restrict__ bias,
             int M, int N, int K, int n_tiles, int mt_per_xcd) {
  __shared__ unsigned short Ash[128 * 64];   // 16 KB
  __shared__ unsigned short Bsh[128 * 64];   // 16 KB
  const int tid  = threadIdx.x;
  const int wv   = tid >> 6, lane = tid & 63;
  const int quad = lane >> 4, l15 = lane & 15;
  const int wr   = wv >> 1, wc = wv & 1;

  const int b = blockIdx.x;
  const int xcd = b & 7, local = b >> 3;
  const int mt = xcd * mt_per_xcd + local / n_tiles;
  const int nt = local % n_tiles;
  const int m0 = mt * 128, n0 = nt * 128;

  // staging: 1024 16B-groups per matrix; p in 0..3, lin = p*256+tid
  // LDS slot lin = (row = lin>>3, cg = lin&7); global group = cg ^ (row&7)
  const unsigned short* pA[4];
  const unsigned short* pB[4];
  #pragma unroll
  for (int p = 0; p < 4; ++p) {
    int lin = p * 256 + tid;
    int row = lin >> 3, g = (lin & 7) ^ (row & 7);
    pA[p] = &A[(size_t)(m0 + row) * K + g * 8];
    pB[p] = &Bt[(size_t)(n0 + row) * K + g * 8];
  }

  f32x4 acc[4][4];
  #pragma unroll
  for (int i = 0; i < 4; ++i)
    #pragma unroll
    for (int j = 0; j < 4; ++j)
      acc[i][j] = (f32x4){0.f, 0.f, 0.f, 0.f};

  for (int k0 = 0; k0 < K; k0 += 64) {
    #pragma unroll
    for (int p = 0; p < 4; ++p)
      async_copy16(pA[p] + k0, &Ash[(p * 256 + tid) * 8]);
    #pragma unroll
    for (int p = 0; p < 4; ++p)
      async_copy16(pB[p] + k0, &Bsh[(p * 256 + tid) * 8]);
    __syncthreads();
    #pragma unroll
    for (int ks = 0; ks < 2; ++ks) {
      const int swz = (((ks * 4 + quad) ^ (l15 & 7)) * 8);
      bf16x8 af[4], bfr[4];
      #pragma unroll
      for (int i = 0; i < 4; ++i)
        af[i] = lds_frag(&Ash[(wr * 64 + i * 16 + l15) * 64 + swz]);
      #pragma unroll
      for (int j = 0; j < 4; ++j)
        bfr[j] = lds_frag(&Bsh[(wc * 64 + j * 16 + l15) * 64 + swz]);
      #pragma unroll
      for (int i = 0; i < 4; ++i)
        #pragma unroll
        for (int j = 0; j < 4; ++j)
          acc[i][j] = __builtin_amdgcn_mfma_f32_16x16x32_bf16(af[i], bfr[j], acc[i][j], 0, 0, 0);
    }
    __syncthreads();
  }

  #pragma unroll
  for (int i = 0; i < 4; ++i) {
    #pragma unroll
    for (int j = 0; j < 4; ++j) {
      int col = n0 + wc * 64 + j * 16 + l15;
      float badd = (bias != nullptr) ? bias[col] : 0.f;
      #pragma unroll
      for (int r = 0; r < 4; ++r) {
        int row = m0 + wr * 64 + i * 16 + quad * 4 + r;
        if constexpr (sizeof(OutT) == 2)
          C[(size_t)row * N + col] = f2bf(acc[i][j][r] + badd);
        else
          C[(size_t)row * N + col] = acc[i][j][r] + badd;
      }
    }
  }
}

// Local attention (unchanged from round 6): one block per (head, window).
// 512 threads / 8 waves: wave wv owns m-tile wv. Two block-wide barriers.
// PV split into two k-halves so the P overlay fits Ksh (4KB/wave/half).
__global__ __launch_bounds__(512, 4)
void attn_local(const unsigned short* __restrict__ qkv,
                unsigned short* __restrict__ out) {
  __shared__ unsigned short Ksh[2 * 256 * 32];   // 32 KB
  __shared__ unsigned short VshT[64 * 256];      // 32 KB
  unsigned short* Psh = Ksh;

  const int tid  = threadIdx.x;
  const int wv   = tid >> 6, lane = tid & 63;
  const int quad = lane >> 4, l15 = lane & 15;
  const int h = blockIdx.x & 7, w = blockIdx.x >> 3;

  // stage K (k-tiled); rows j<128 of window 0 are zeros
  #pragma unroll
  for (int p = 0; p < 4; ++p) {
    int c = p * 512 + tid;                 // 2048 = 256 rows x 8 vec8-groups
    int j = c >> 3, sub = c & 7;
    u32x4 kvv = (u32x4){0, 0, 0, 0};
    if (!(w == 0 && j < 128)) {
      size_t base = (size_t)((w - 1) * 128 + j) * 1536 + h * 64 + sub * 8;
      kvv = *(const u32x4*)&qkv[base + 512];
    }
    *(u32x4*)&Ksh[(sub >> 2) * 8192 + j * 32 + (sub & 3) * 8] = kvv;
  }
  // stage V^T
  {
    const int n = tid & 63, kb8 = tid >> 6;
    #pragma unroll
    for (int kk = 0; kk < 4; ++kk) {
      int kb = kk * 8 + kb8;               // group 0..31, k0 = kb*8
      unsigned short tmp[8];
      if (w == 0 && kb < 16) {
        #pragma unroll
        for (int j = 0; j < 8; ++j) tmp[j] = 0;
      } else {
        #pragma unroll
        for (int j = 0; j < 8; ++j)
          tmp[j] = qkv[(size_t)((w - 1) * 128 + kb * 8 + j) * 1536 + 1024 + h * 64 + n];
      }
      *(u32x4*)&VshT[n * 256 + ((kb ^ (n & 7)) * 8)] = *(u32x4*)tmp;
    }
  }

  // Q fragments straight from global
  bf16x8 qf[2];
  {
    int tok = w * 128 + wv * 16 + l15;
    #pragma unroll
    for (int ks = 0; ks < 2; ++ks)
      qf[ks] = __builtin_bit_cast(
          bf16x8, *(const u32x4*)&qkv[(size_t)tok * 1536 + h * 64 + ks * 32 + quad * 8]);
  }

  __syncthreads();   // staging visible block-wide

  // scores
  float s[16][4];
  #pragma unroll
  for (int nt = 0; nt < 16; ++nt) {
    bf16x8 kf0 = lds_frag(&Ksh[0    + (nt * 16 + l15) * 32 + quad * 8]);
    bf16x8 kf1 = lds_frag(&Ksh[8192 + (nt * 16 + l15) * 32 + quad * 8]);
    f32x4 a = (f32x4){0.f, 0.f, 0.f, 0.f};
    a = __builtin_amdgcn_mfma_f32_16x16x32_bf16(qf[0], kf0, a, 0, 0, 0);
    a = __builtin_amdgcn_mfma_f32_16x16x32_bf16(qf[1], kf1, a, 0, 0, 0);
    #pragma unroll
    for (int r = 0; r < 4; ++r) s[nt][r] = a[r];
  }

  __syncthreads();   // all waves' Ksh reads complete -> safe to overlay P

  // masked softmax in registers
  #pragma unroll
  for (int r = 0; r < 4; ++r) {
    int lim = wv * 16 + quad * 4 + r + 128;
    float mx = -3.0e38f;
    #pragma unroll
    for (int nt = 0; nt < 16; ++nt) {
      float v = ((nt * 16 + l15) <= lim) ? s[nt][r] * 0.125f : -3.0e38f;
      s[nt][r] = v;
      mx = fmaxf(mx, v);
    }
    mx = fmaxf(mx, __shfl_xor(mx, 1));
    mx = fmaxf(mx, __shfl_xor(mx, 2));
    mx = fmaxf(mx, __shfl_xor(mx, 4));
    mx = fmaxf(mx, __shfl_xor(mx, 8));
    float sum = 0.f;
    #pragma unroll
    for (int nt = 0; nt < 16; ++nt) {
      float p = __expf(s[nt][r] - mx);
      s[nt][r] = p;
      sum += p;
    }
    sum += __shfl_xor(sum, 1);
    sum += __shfl_xor(sum, 2);
    sum += __shfl_xor(sum, 4);
    sum += __shfl_xor(sum, 8);
    float inv = 1.f / sum;
    #pragma unroll
    for (int nt = 0; nt < 16; ++nt) s[nt][r] *= inv;
  }

  // split PV through wave-private 4KB region
  f32x4 o[4];
  #pragma unroll
  for (int n2 = 0; n2 < 4; ++n2) o[n2] = (f32x4){0.f, 0.f, 0.f, 0.f};
  #pragma unroll
  for (int half = 0; half < 2; ++half) {
    if (half) {
      asm volatile("s_waitcnt lgkmcnt(0)" ::: "memory");
      __builtin_amdgcn_sched_barrier(0);
    }
    #pragma unroll
    for (int nt2 = 0; nt2 < 8; ++nt2) {
      int nt = half * 8 + nt2;
      #pragma unroll
      for (int r = 0; r < 4; ++r)
        Psh[wv * 2048 + (nt2 >> 1) * 512 + (quad * 4 + r) * 32 + (nt2 & 1) * 16 + l15] =
            f2bf(s[nt][r]);
    }
    asm volatile("s_waitcnt lgkmcnt(0)" ::: "memory");
    __builtin_amdgcn_sched_barrier(0);
    #pragma unroll
    for (int ks2 = 0; ks2 < 4; ++ks2) {
      int ks = half * 4 + ks2;
      bf16x8 pa = lds_frag(&Psh[wv * 2048 + ks2 * 512 + l15 * 32 + quad * 8]);
      #pragma unroll
      for (int n2 = 0; n2 < 4; ++n2) {
        bf16x8 vb = lds_frag(&VshT[(n2 * 16 + l15) * 256 + (((ks * 4 + quad) ^ (l15 & 7)) * 8)]);
        o[n2] = __builtin_amdgcn_mfma_f32_16x16x32_bf16(pa, vb, o[n2], 0, 0, 0);
      }
    }
  }
  int tokb = w * 128 + wv * 16 + quad * 4;
  #pragma unroll
  for (int n2 = 0; n2 < 4; ++n2)
    #pragma unroll
    for (int r = 0; r < 4; ++r)
      out[(size_t)(tokb + r) * 512 + h * 64 + n2 * 16 + l15] = f2bf(o[n2][r]);
}

extern "C" void kernel_launch(void* const* d_in, const int* in_sizes, int n_in,
                              void* d_out, int out_size, void* d_ws, size_t ws_size,
                              hipStream_t stream) {
  const float* x     = (const float*)d_in[0];  // 16384 x 1024 fp32
  const float* w_qkv = (const float*)d_in[1];  // 1024 x 1536 fp32
  const float* w_out = (const float*)d_in[2];  // 512 x 1024 fp32
  const float* b_out = (const float*)d_in[3];  // 1024 fp32
  float* out = (float*)d_out;                  // 16384 x 1024 fp32

  char* ws = (char*)d_ws;
  unsigned short* xb    = (unsigned short*)ws;                     // 16384x1024 bf16 (32 MB)
  unsigned short* wqkvT = (unsigned short*)(ws + 33554432);        // 1536x1024 (3 MB)
  unsigned short* woutT = (unsigned short*)(ws + 36700160);        // 1024x512  (1 MB)
  unsigned short* qkv   = (unsigned short*)(ws + 37748736);        // 16384x1536 (48 MB)
  unsigned short* attno = (unsigned short*)(ws + 88080384);        // 16384x512 (16 MB)

  // fused prep: cast (8192 blocks) + transpose w_qkv (1536) + transpose w_out (512)
  prep_k<<<10240, 256, 0, stream>>>(x, xb, w_qkv, wqkvT, w_out, woutT);
  // QKV: 128 m-tiles x 12 n-tiles; 16 m-tiles per xcd
  gemm_bt<unsigned short><<<1536, 256, 0, stream>>>(
      xb, wqkvT, qkv, nullptr, 16384, 1536, 1024, 12, 16);
  attn_local<<<1024, 512, 0, stream>>>(qkv, attno);
  // out-proj: 128 m-tiles x 8 n-tiles; 16 m-tiles per xcd
  gemm_bt<float><<<1024, 256, 0, stream>>>(
      attno, woutT, out, b_out, 16384, 1024, 512, 8, 16);
}